// Round 1
// baseline (88.925 us; speedup 1.0000x reference)
//
#include <hip/hip_runtime.h>
#include <math.h>

#define Vv 200000
#define Tt 50
#define Dd 64
#define Bb 4096
#define Ss 64

__device__ __forceinline__ float wsum(float v) {
#pragma unroll
  for (int m = 32; m >= 1; m >>= 1) v += __shfl_xor(v, m, 64);
  return v;
}
__device__ __forceinline__ float wmax(float v) {
#pragma unroll
  for (int m = 32; m >= 1; m >>= 1) v = fmaxf(v, __shfl_xor(v, m, 64));
  return v;
}

// log(q) with q = (log(id+2)-log(id+1))/log(V+1), computed cancellation-free:
// log(id+2)-log(id+1) == log1p(1/(id+1))
__device__ __forceinline__ float logq_f(int id) {
  float idf = (float)id;
  float r = log1pf(1.0f / (idf + 1.0f));
  return logf(r * (1.0f / 12.2060776f));  // 12.2060776 = ln(200001)
}

__global__ __launch_bounds__(256) void u2i_kernel(
    const float* __restrict__ item_table,
    const float* __restrict__ pos_table,
    const float* __restrict__ att_W,
    const float* __restrict__ att_b,
    const float* __restrict__ prelu_alpha,
    const float* __restrict__ zero_bias,
    const int* __restrict__ items_id,
    const int* __restrict__ position_id,
    const int* __restrict__ target_id,
    const int* __restrict__ keys_length,
    const int* __restrict__ sampled_ids,
    float* __restrict__ out_vec,   // [B]
    float* __restrict__ loss_ws)   // [B]
{
  __shared__ float sampT[Dd][Ss + 1];  // [d][s], +1 pad -> 2-way (free) bank aliasing
  __shared__ float ut1_lds[4][Dd];

  const int tid = threadIdx.x;
  const int lane = tid & 63;
  const int w = tid >> 6;
  const int b = (blockIdx.x << 2) | w;

  // Stage sampled-id embedding rows transposed into LDS (shared by all 4 waves).
#pragma unroll
  for (int k = 0; k < (Ss * Dd) / 256; ++k) {
    int e = tid + k * 256;
    int s = e >> 6, d0 = e & 63;
    sampT[d0][s] = item_table[(size_t)sampled_ids[s] * Dd + d0];
  }
  __syncthreads();

  const int d = lane;
  const float Wi = att_W[d];
  const float Wp = att_W[Dd + d];
  const float bias = att_b[0];
  const int kl = keys_length[b];

  const int* ids_b = items_id + b * Tt;
  const int* pos_b = position_id + b * Tt;

  float item_v[Tt];
  unsigned long long pad_mask = 0ull;
  float myscore = 0.0f;  // lane t holds score[t] after the loop (t < 50)

#pragma unroll
  for (int t = 0; t < Tt; ++t) {
    int iid = ids_b[t];
    int pid = pos_b[t];
    float iv = item_table[(size_t)iid * Dd + d];
    float pv = pos_table[pid * Dd + d];
    item_v[t] = iv;
    if (iid != 0) pad_mask |= (1ull << t);
    float s = wsum(iv * Wi + pv * Wp);      // all lanes get the full sum
    float sc = tanhf(s + bias);
    if (lane == t) myscore = sc;
  }

  // Softmax over t (lane-parallel): valid iff lane < kl (kl <= 50)
  float scv = (lane < kl) ? myscore : -INFINITY;
  float m = wmax(scv);
  float e = (lane < kl) ? expf(myscore - m) : 0.0f;
  float denom = wsum(e);
  float inv_denom = 1.0f / denom;

  // Weighted pooling + ut_1 (exclude t = T-1, apply padding mask)
  float sum_pool = 0.0f, ut1 = 0.0f;
#pragma unroll
  for (int t = 0; t < Tt; ++t) {
    float wt = __shfl(e, t, 64) * inv_denom;
    float v = wt * item_v[t];
    sum_pool += v;
    if (t < Tt - 1 && ((pad_mask >> t) & 1ull)) ut1 += v;
  }

  // PReLU + output dot with target embedding
  float alpha = prelu_alpha[d];
  float sp = (sum_pool > 0.0f) ? sum_pool : alpha * sum_pool;
  int tgt = target_id[b];
  float tv = item_table[(size_t)tgt * Dd + d];
  float outb = wsum(sp * tv);
  if (lane == 0) out_vec[b] = outb;

  // True logit
  int result = ids_b[kl - 1];
  float tw = item_table[(size_t)result * Dd + d];
  float tl = wsum(ut1 * tw) + zero_bias[result] - logq_f(result);

  // Sampled logits: ut1 (distributed over lanes=d) -> LDS, then lane=s does the dot
  ut1_lds[w][d] = ut1;
  __syncthreads();

  int sid = sampled_ids[lane];
  float acc = 0.0f;
#pragma unroll
  for (int dd = 0; dd < Dd; ++dd)
    acc += ut1_lds[w][dd] * sampT[dd][lane];
  float sl = acc + zero_bias[sid] - logq_f(sid);
  if (sid == result) sl -= 1e9f;

  // loss_b = logsumexp([tl, sl...]) - tl
  float mx = fmaxf(tl, wmax(sl));
  float se = wsum(expf(sl - mx)) + expf(tl - mx);
  float loss_b = (mx + logf(se)) - tl;
  if (lane == 0) loss_ws[b] = loss_b;
}

__global__ __launch_bounds__(256) void loss_reduce_kernel(
    const float* __restrict__ ws, float* __restrict__ out_loss) {
  __shared__ float red[4];
  float acc = 0.0f;
  for (int i = threadIdx.x; i < Bb; i += 256) acc += ws[i];
  acc = wsum(acc);
  if ((threadIdx.x & 63) == 0) red[threadIdx.x >> 6] = acc;
  __syncthreads();
  if (threadIdx.x == 0)
    out_loss[0] = (red[0] + red[1] + red[2] + red[3]) * (1.0f / (float)Bb);
}

extern "C" void kernel_launch(void* const* d_in, const int* in_sizes, int n_in,
                              void* d_out, int out_size, void* d_ws, size_t ws_size,
                              hipStream_t stream) {
  const float* item_table  = (const float*)d_in[0];
  const float* pos_table   = (const float*)d_in[1];
  const float* att_W       = (const float*)d_in[2];
  const float* att_b       = (const float*)d_in[3];
  const float* prelu_alpha = (const float*)d_in[4];
  const float* zero_bias   = (const float*)d_in[5];
  const int* items_id      = (const int*)d_in[6];
  const int* position_id   = (const int*)d_in[7];
  const int* target_id     = (const int*)d_in[8];
  const int* keys_length   = (const int*)d_in[9];
  const int* sampled_ids   = (const int*)d_in[10];

  float* out = (float*)d_out;         // [0..4095]=output, [4096]=loss
  float* loss_ws = (float*)d_ws;      // B floats

  u2i_kernel<<<Bb / 4, 256, 0, stream>>>(
      item_table, pos_table, att_W, att_b, prelu_alpha, zero_bias,
      items_id, position_id, target_id, keys_length, sampled_ids,
      out, loss_ws);
  loss_reduce_kernel<<<1, 256, 0, stream>>>(loss_ws, out + Bb);
}

// Round 2
// 31.328 us; speedup vs baseline: 2.8385x; 2.8385x over previous
//
#include <hip/hip_runtime.h>
#include <hip/hip_bf16.h>
#include <math.h>

#define Tt 50
#define Dd 64
#define Bb 4096
#define Ss 64
#define ROWP 68  // padded row length (ushorts): 136 B rows -> 8B-aligned ushort4 reads

__device__ __forceinline__ float wsum(float v) {
#pragma unroll
  for (int m = 32; m >= 1; m >>= 1) v += __shfl_xor(v, m, 64);
  return v;
}
__device__ __forceinline__ float wmax(float v) {
#pragma unroll
  for (int m = 32; m >= 1; m >>= 1) v = fmaxf(v, __shfl_xor(v, m, 64));
  return v;
}
__device__ __forceinline__ float bf2f(unsigned short u) {
  return __uint_as_float(((unsigned)u) << 16);
}
__device__ __forceinline__ unsigned short f2bf(float f) {
  __hip_bfloat16 h = __float2bfloat16(f);  // RNE
  return __builtin_bit_cast(unsigned short, h);
}
// log(q), cancellation-free: log(id+2)-log(id+1) == log1p(1/(id+1))
__device__ __forceinline__ float logq_f(int id) {
  float idf = (float)id;
  float r = log1pf(1.0f / (idf + 1.0f));
  return logf(r * (1.0f / 12.2060776f));  // ln(200001) = 12.2060776
}

__global__ __launch_bounds__(256) void u2i_kernel(
    const float* __restrict__ item_table,
    const float* __restrict__ pos_table,
    const float* __restrict__ att_W,
    const float* __restrict__ att_b,
    const float* __restrict__ prelu_alpha,
    const float* __restrict__ zero_bias,
    const int* __restrict__ items_id,
    const int* __restrict__ position_id,
    const int* __restrict__ target_id,
    const int* __restrict__ keys_length,
    const int* __restrict__ sampled_ids,
    float* __restrict__ out_vec,   // [B]
    float* __restrict__ loss_ws)   // [B]
{
  __shared__ unsigned short itemsB[4][Tt][ROWP];  // 27200 B (bf16)
  __shared__ unsigned short sampB[Ss][ROWP];      //  8704 B (bf16, [s][d])
  __shared__ float attWi[Dd];                     //   256 B
  __shared__ float pos_score[52];                 //   208 B
  __shared__ float wv[4][Dd];                     //  1024 B
  __shared__ float ut1_lds[4][Dd];                //  1024 B

  const int tid = threadIdx.x;
  const int lane = tid & 63;
  const int w = tid >> 6;
  const int b = (blockIdx.x << 2) | w;

  // per-lane ids (lane plays role of t here)
  int idreg = 0, pidreg = 0;
  if (lane < Tt) {
    idreg = items_id[b * Tt + lane];
    pidreg = position_id[b * Tt + lane];
  }
  const int kl = keys_length[b];

  // ---- staging (whole block / per wave) ----
#pragma unroll
  for (int k = 0; k < (Ss * Dd) / 256; ++k) {
    int e = tid + k * 256;
    int s = e >> 6, d0 = e & 63;
    sampB[s][d0] = f2bf(item_table[(size_t)sampled_ids[s] * Dd + d0]);
  }
  if (tid < Dd) attWi[tid] = att_W[tid];

  // this wave's 50 item rows -> LDS (coalesced 256B wave loads, bf16 store)
#pragma unroll
  for (int t = 0; t < Tt; ++t) {
    int iid = __shfl(idreg, t, 64);
    float iv = item_table[(size_t)iid * Dd + lane];
    itemsB[w][t][lane] = f2bf(iv);
  }

  // pos_score[p] = dot(pos_table[p], Wp)  (p = w + 4*i, once per block)
  const float wp_lane = att_W[Dd + lane];
#pragma unroll
  for (int i = 0; i < 13; ++i) {
    int p = w + 4 * i;
    if (p < Tt) {
      float s = wsum(pos_table[p * Dd + lane] * wp_lane);
      if (lane == 0) pos_score[p] = s;
    }
  }
  __syncthreads();

  // ---- phase 2: lane = t -> score, softmax ----
  const int trow = (lane < Tt) ? lane : (Tt - 1);
  const ushort4* rowp = (const ushort4*)&itemsB[w][trow][0];
  float a0 = 0, a1 = 0, a2 = 0, a3 = 0;
#pragma unroll
  for (int q = 0; q < 16; ++q) {
    ushort4 u = rowp[q];
    a0 += bf2f(u.x) * attWi[4 * q + 0];
    a1 += bf2f(u.y) * attWi[4 * q + 1];
    a2 += bf2f(u.z) * attWi[4 * q + 2];
    a3 += bf2f(u.w) * attWi[4 * q + 3];
  }
  float sc = tanhf((a0 + a1) + (a2 + a3) + pos_score[pidreg] + att_b[0]);
  float scv = (lane < kl) ? sc : -INFINITY;
  float m = wmax(scv);
  float e = (lane < kl) ? expf(sc - m) : 0.0f;
  float denom = wsum(e);
  wv[w][lane] = e / denom;  // lanes >= kl store 0
  unsigned long long mask = __ballot(lane < Tt - 1 && idreg != 0);
  __syncthreads();

  // ---- phase 3: lane = d -> pooling, output, true logit ----
  const int d = lane;
  float sum_pool = 0.0f, ut1 = 0.0f;
  const float4* wvp = (const float4*)&wv[w][0];
#pragma unroll
  for (int q = 0; q < 12; ++q) {
    float4 wf = wvp[q];
    float i0 = bf2f(itemsB[w][4 * q + 0][d]);
    float i1 = bf2f(itemsB[w][4 * q + 1][d]);
    float i2 = bf2f(itemsB[w][4 * q + 2][d]);
    float i3 = bf2f(itemsB[w][4 * q + 3][d]);
    sum_pool += wf.x * i0 + wf.y * i1 + wf.z * i2 + wf.w * i3;
    ut1 += ((mask >> (4 * q + 0)) & 1ull) ? wf.x * i0 : 0.0f;
    ut1 += ((mask >> (4 * q + 1)) & 1ull) ? wf.y * i1 : 0.0f;
    ut1 += ((mask >> (4 * q + 2)) & 1ull) ? wf.z * i2 : 0.0f;
    ut1 += ((mask >> (4 * q + 3)) & 1ull) ? wf.w * i3 : 0.0f;
  }
  {
    float w48 = wv[w][48], w49 = wv[w][49];
    float i48 = bf2f(itemsB[w][48][d]);
    float i49 = bf2f(itemsB[w][49][d]);
    sum_pool += w48 * i48 + w49 * i49;
    ut1 += ((mask >> 48) & 1ull) ? w48 * i48 : 0.0f;  // t=49 always excluded
  }

  float alpha = prelu_alpha[d];
  float sp = (sum_pool > 0.0f) ? sum_pool : alpha * sum_pool;
  int tgt = target_id[b];
  float tv = item_table[(size_t)tgt * Dd + d];
  float outb = wsum(sp * tv);
  if (lane == 0) out_vec[b] = outb;

  int result = __shfl(idreg, kl - 1, 64);
  float tw = item_table[(size_t)result * Dd + d];
  float tl = wsum(ut1 * tw) + zero_bias[result] - logq_f(result);
  ut1_lds[w][d] = ut1;
  __syncthreads();

  // ---- phase 4: lane = s -> sampled logits + loss ----
  int sid = sampled_ids[lane];
  const ushort4* sp4 = (const ushort4*)&sampB[lane][0];
  const float4* up = (const float4*)&ut1_lds[w][0];
  float acc = 0.0f;
#pragma unroll
  for (int q = 0; q < 16; ++q) {
    ushort4 u = sp4[q];
    float4 uv = up[q];  // uniform address -> broadcast
    acc += bf2f(u.x) * uv.x + bf2f(u.y) * uv.y + bf2f(u.z) * uv.z +
           bf2f(u.w) * uv.w;
  }
  float sl = acc + zero_bias[sid] - logq_f(sid);
  if (sid == result) sl -= 1e9f;

  float mx = fmaxf(tl, wmax(sl));
  float se = wsum(expf(sl - mx)) + expf(tl - mx);
  if (lane == 0) loss_ws[b] = (mx + logf(se)) - tl;
}

__global__ __launch_bounds__(256) void loss_reduce_kernel(
    const float* __restrict__ ws, float* __restrict__ out_loss) {
  __shared__ float red[4];
  float acc = 0.0f;
  for (int i = threadIdx.x; i < Bb; i += 256) acc += ws[i];
  acc = wsum(acc);
  if ((threadIdx.x & 63) == 0) red[threadIdx.x >> 6] = acc;
  __syncthreads();
  if (threadIdx.x == 0)
    out_loss[0] = (red[0] + red[1] + red[2] + red[3]) * (1.0f / (float)Bb);
}

extern "C" void kernel_launch(void* const* d_in, const int* in_sizes, int n_in,
                              void* d_out, int out_size, void* d_ws, size_t ws_size,
                              hipStream_t stream) {
  const float* item_table  = (const float*)d_in[0];
  const float* pos_table   = (const float*)d_in[1];
  const float* att_W       = (const float*)d_in[2];
  const float* att_b       = (const float*)d_in[3];
  const float* prelu_alpha = (const float*)d_in[4];
  const float* zero_bias   = (const float*)d_in[5];
  const int* items_id      = (const int*)d_in[6];
  const int* position_id   = (const int*)d_in[7];
  const int* target_id     = (const int*)d_in[8];
  const int* keys_length   = (const int*)d_in[9];
  const int* sampled_ids   = (const int*)d_in[10];

  float* out = (float*)d_out;     // [0..4095]=output, [4096]=loss
  float* loss_ws = (float*)d_ws;  // B floats

  u2i_kernel<<<Bb / 4, 256, 0, stream>>>(
      item_table, pos_table, att_W, att_b, prelu_alpha, zero_bias,
      items_id, position_id, target_id, keys_length, sampled_ids,
      out, loss_ws);
  loss_reduce_kernel<<<1, 256, 0, stream>>>(loss_ws, out + Bb);
}